// Round 1
// baseline (3635.920 us; speedup 1.0000x reference)
//
#include <hip/hip_runtime.h>
#include <hip/hip_bf16.h>
#include <math.h>

#define NN 50000
#define NE 800000

// ---------------- helpers ----------------

__global__ void k_zero(float* __restrict__ p, int n) {
    int i = blockIdx.x * blockDim.x + threadIdx.x;
    if (i < n) p[i] = 0.f;
}

__global__ void k_deg(const int* __restrict__ src, const int* __restrict__ dst,
                      float* __restrict__ din, float* __restrict__ dout, int E) {
    int e = blockIdx.x * blockDim.x + threadIdx.x;
    if (e < E) {
        atomicAdd(&din[dst[e]], 1.f);
        atomicAdd(&dout[src[e]], 1.f);
    }
}

__global__ void k_invsqrt(float* __restrict__ p, int n) {
    int i = blockIdx.x * blockDim.x + threadIdx.x;
    if (i < n) {
        float v = p[i];
        v = v < 1.f ? 1.f : v;
        p[i] = 1.f / sqrtf(v);
    }
}

// y[dst[e], :] += x[src[e], :] * scale[src[e]]    (scale nullable)
template <int D>
__global__ void k_spmm(const float* __restrict__ x, const int* __restrict__ src,
                       const int* __restrict__ dst, const float* __restrict__ scale,
                       float* __restrict__ y, int E) {
    constexpr int TPE = D / 4;  // threads per edge (float4 each)
    int idx = blockIdx.x * blockDim.x + threadIdx.x;
    int e = idx / TPE;
    int c = idx % TPE;
    if (e >= E) return;
    int s = src[e], d = dst[e];
    float sc = scale ? scale[s] : 1.f;
    float4 v = ((const float4*)(x + (size_t)s * D))[c];
    float* yp = y + (size_t)d * D + c * 4;
    atomicAdd(yp + 0, v.x * sc);
    atomicAdd(yp + 1, v.y * sc);
    atomicAdd(yp + 2, v.z * sc);
    atomicAdd(yp + 3, v.w * sc);
}

// out = f - S * din[row]   (lap combine), vectorized float4
template <int D>
__global__ void k_lapcomb(float* __restrict__ out, const float* __restrict__ f,
                          const float* __restrict__ S, const float* __restrict__ din, int N) {
    constexpr int TPR = D / 4;
    int idx = blockIdx.x * blockDim.x + threadIdx.x;
    if (idx >= N * TPR) return;
    int row = idx / TPR;
    float4 fv = ((const float4*)f)[idx];
    float4 sv = ((const float4*)S)[idx];
    float d = din[row];
    float4 o;
    o.x = fv.x - sv.x * d;
    o.y = fv.y - sv.y * d;
    o.z = fv.z - sv.z * d;
    o.w = fv.w - sv.w * d;
    ((float4*)out)[idx] = o;
}

// combine W3 branch blocks into 3 effective [64,64] weights
__global__ void k_wc(const float* __restrict__ W3, float* __restrict__ wc) {
    int i = blockIdx.x * blockDim.x + threadIdx.x;  // 4096
    if (i >= 4096) return;
    int r = i >> 6, c = i & 63;
    float w0 = W3[(0 * 64 + r) * 64 + c];
    float w1 = W3[(1 * 64 + r) * 64 + c];
    float w2 = W3[(2 * 64 + r) * 64 + c];
    float w3 = W3[(3 * 64 + r) * 64 + c];
    float w4 = W3[(4 * 64 + r) * 64 + c];
    wc[i]        = 3.f * w0;                                   // coeff of h
    wc[4096 + i] = -3.f * w0 + 3.f * w1 + w3;                  // coeff of L1 h
    wc[8192 + i] = 0.75f * w0 - 1.5f * w1 + 0.75f * w2 + w4;   // coeff of L2 h
}

// ---------------- generic f32 GEMM: C[N,M] = relu?( A[N,K] @ W[K,M] + bias ) ----------------
// A given as up to 3 K-tiles of 64 (pointer + leading dim each); optional row scale on A.

struct ASeg { const float* p; int ld; };
struct AArgs { ASeg s[3]; };

template <int M, bool RELU>
__launch_bounds__(256)
__global__ void k_gemm(AArgs A, int K, const float* __restrict__ W,
                       const float* __restrict__ bias, const float* __restrict__ rscale,
                       float* __restrict__ C, int N) {
    constexpr int TX = M / 8;        // threads along cols (8 outputs each)
    constexpr int ROWS = 256 / TX;   // rows per block
    __shared__ float Ws[64 * M];
    __shared__ float As[ROWS * 65];  // +1 pad: broadcast read lands on distinct banks per ty
    int tx = threadIdx.x, ty = threadIdx.y;
    int tid = ty * TX + tx;
    int row0 = blockIdx.x * ROWS;
    float acc[8];
#pragma unroll
    for (int j = 0; j < 8; j++) acc[j] = 0.f;
    int nt = K / 64;
    for (int t = 0; t < nt; t++) {
        const float* Ap = A.s[t].p;
        int ld = A.s[t].ld;
        for (int i = tid; i < ROWS * 64; i += 256) {
            int r = i >> 6, k = i & 63;
            int row = row0 + r;
            float v = 0.f;
            if (row < N) {
                v = Ap[(size_t)row * ld + k];
                if (rscale) v *= rscale[row];
            }
            As[r * 65 + k] = v;
        }
        const float* Wt = W + t * 64 * M;
        for (int i = tid; i < 64 * M; i += 256) Ws[i] = Wt[i];
        __syncthreads();
#pragma unroll 4
        for (int k = 0; k < 64; k++) {
            float av = As[ty * 65 + k];
#pragma unroll
            for (int j = 0; j < 8; j++) acc[j] += av * Ws[k * M + tx * 8 + j];
        }
        __syncthreads();
    }
    int row = row0 + ty;
    if (row < N) {
#pragma unroll
        for (int j = 0; j < 8; j++) {
            float v = acc[j] + bias[tx * 8 + j];
            if (RELU) v = fmaxf(v, 0.f);
            C[(size_t)row * M + tx * 8 + j] = v;
        }
    }
}

// out[N,2] = P[N,64] @ W4[64,2] + b4 — 4 lanes per node, shuffle reduce
__global__ void k_out(const float* __restrict__ P, const float* __restrict__ W4,
                      const float* __restrict__ b4, float* __restrict__ out, int N) {
    __shared__ float Ws[128];
    int tid = threadIdx.x;
    if (tid < 128) Ws[tid] = W4[tid];
    __syncthreads();
    int g = blockIdx.x * 64 + (tid >> 2);  // node
    int q = tid & 3;
    float a0 = 0.f, a1 = 0.f;
    if (g < N) {
        const float4* Pr = (const float4*)(P + (size_t)g * 64);
#pragma unroll
        for (int j = 0; j < 4; j++) {
            float4 v = Pr[q * 4 + j];
            int k = q * 16 + j * 4;
            a0 += v.x * Ws[(k + 0) * 2] + v.y * Ws[(k + 1) * 2] +
                  v.z * Ws[(k + 2) * 2] + v.w * Ws[(k + 3) * 2];
            a1 += v.x * Ws[(k + 0) * 2 + 1] + v.y * Ws[(k + 1) * 2 + 1] +
                  v.z * Ws[(k + 2) * 2 + 1] + v.w * Ws[(k + 3) * 2 + 1];
        }
    }
    a0 += __shfl_down(a0, 2); a0 += __shfl_down(a0, 1);
    a1 += __shfl_down(a1, 2); a1 += __shfl_down(a1, 1);
    if (g < N && q == 0) {
        out[(size_t)g * 2 + 0] = a0 + b4[0];
        out[(size_t)g * 2 + 1] = a1 + b4[1];
    }
}

static inline int cdiv(int a, int b) { return (a + b - 1) / b; }

extern "C" void kernel_launch(void* const* d_in, const int* in_sizes, int n_in,
                              void* d_out, int out_size, void* d_ws, size_t ws_size,
                              hipStream_t stream) {
    const int N = NN, E = NE;
    const float* in_feat = (const float*)d_in[0];
    const int* src = (const int*)d_in[1];
    const int* dst = (const int*)d_in[2];
    const float* W1 = (const float*)d_in[3];
    const float* b1 = (const float*)d_in[4];
    const float* W2 = (const float*)d_in[5];
    const float* b2 = (const float*)d_in[6];
    const float* W3 = (const float*)d_in[7];
    const float* b3 = (const float*)d_in[8];
    const float* W4 = (const float*)d_in[9];
    const float* b4 = (const float*)d_in[10];
    const float* Wg1 = (const float*)d_in[11];
    const float* bg1 = (const float*)d_in[12];
    const float* Wg2 = (const float*)d_in[13];
    const float* bg2 = (const float*)d_in[14];

    float* out = (float*)d_out;                 // [N,2]
    float* emb = out + (size_t)N * 2;           // [N,128]

    float* ws = (float*)d_ws;
    float* din = ws;                 // [N]
    float* dout = din + N;           // [N]
    float* bufA = dout + N;          // [N,64]  h1, later P
    float* bufH = bufA + (size_t)64 * N;   // [N,64]  h
    float* bufL1 = bufH + (size_t)64 * N;  // [N,64]  L1, later g1
    float* S = bufL1 + (size_t)64 * N;     // [N,64]  spmm accum
    float* S128 = S + (size_t)64 * N;      // [N,128] spmm accum (L2 aliases first half)
    float* bufL2 = S128;                   // [N,64]  (dead before S128 is used)
    float* wc = S128 + (size_t)128 * N;    // [3,64,64]

    dim3 blk64(8, 32);    // M=64
    dim3 blk128(16, 16);  // M=128
    int gemmBlocks64 = cdiv(N, 32);
    int gemmBlocks128 = cdiv(N, 16);

    // degrees -> din = deg_in^-1/2, dout = deg_out^-1/2
    k_zero<<<cdiv(2 * N, 256), 256, 0, stream>>>(din, 2 * N);
    k_deg<<<cdiv(E, 256), 256, 0, stream>>>(src, dst, din, dout, E);
    k_invsqrt<<<cdiv(2 * N, 256), 256, 0, stream>>>(din, 2 * N);

    // h = relu(relu(in_feat@W1+b1)@W2+b2)
    AArgs a1; a1.s[0] = {in_feat, 128}; a1.s[1] = {in_feat + 64, 128}; a1.s[2] = {nullptr, 0};
    k_gemm<64, true><<<gemmBlocks64, blk64, 0, stream>>>(a1, 128, W1, b1, nullptr, bufA, N);
    AArgs a2; a2.s[0] = {bufA, 64}; a2.s[1] = {nullptr, 0}; a2.s[2] = {nullptr, 0};
    k_gemm<64, true><<<gemmBlocks64, blk64, 0, stream>>>(a2, 64, W2, b2, nullptr, bufH, N);

    // L1 = lap(h), L2 = lap(L1)
    k_zero<<<cdiv(64 * N, 256), 256, 0, stream>>>(S, 64 * N);
    k_spmm<64><<<cdiv(E * 16, 256), 256, 0, stream>>>(bufH, src, dst, din, S, E);
    k_lapcomb<64><<<cdiv(N * 16, 256), 256, 0, stream>>>(bufL1, bufH, S, din, N);
    k_zero<<<cdiv(64 * N, 256), 256, 0, stream>>>(S, 64 * N);
    k_spmm<64><<<cdiv(E * 16, 256), 256, 0, stream>>>(bufL1, src, dst, din, S, E);
    k_lapcomb<64><<<cdiv(N * 16, 256), 256, 0, stream>>>(bufL2, bufL1, S, din, N);

    // folded branch weights, P = relu([h|L1|L2] @ Wc + b3), out = P@W4+b4
    k_wc<<<16, 256, 0, stream>>>(W3, wc);
    AArgs a3; a3.s[0] = {bufH, 64}; a3.s[1] = {bufL1, 64}; a3.s[2] = {bufL2, 64};
    k_gemm<64, true><<<gemmBlocks64, blk64, 0, stream>>>(a3, 192, wc, b3, nullptr, bufA, N);
    k_out<<<cdiv(N, 64), 256, 0, stream>>>(bufA, W4, b4, out, N);

    // GCN branch: emb = gconv(relu(gconv(in_feat,Wg1,bg1)),Wg2,bg2)
    k_zero<<<cdiv(128 * N, 256), 256, 0, stream>>>(S128, 128 * N);
    k_spmm<128><<<cdiv(E * 32, 256), 256, 0, stream>>>(in_feat, src, dst, dout, S128, E);
    AArgs a5; a5.s[0] = {S128, 128}; a5.s[1] = {S128 + 64, 128}; a5.s[2] = {nullptr, 0};
    k_gemm<64, true><<<gemmBlocks64, blk64, 0, stream>>>(a5, 128, Wg1, bg1, din, bufL1, N);
    k_zero<<<cdiv(64 * N, 256), 256, 0, stream>>>(S, 64 * N);
    k_spmm<64><<<cdiv(E * 16, 256), 256, 0, stream>>>(bufL1, src, dst, dout, S, E);
    AArgs a6; a6.s[0] = {S, 64}; a6.s[1] = {nullptr, 0}; a6.s[2] = {nullptr, 0};
    k_gemm<128, false><<<gemmBlocks128, blk128, 0, stream>>>(a6, 64, Wg2, bg2, din, emb, N);
}

// Round 2
// 598.424 us; speedup vs baseline: 6.0758x; 6.0758x over previous
//
#include <hip/hip_runtime.h>
#include <hip/hip_bf16.h>
#include <math.h>

#define NN 50000
#define NE 800000

static inline int cdiv(int a, int b) { return (a + b - 1) / b; }

// ---------------- CSR build ----------------

__global__ void k_zero_i(int* __restrict__ p, int n) {
    int i = blockIdx.x * blockDim.x + threadIdx.x;
    if (i < n) p[i] = 0;
}

__global__ void k_hist(const int* __restrict__ src, const int* __restrict__ dst,
                       int* __restrict__ degin, int* __restrict__ degout, int E) {
    int e = blockIdx.x * blockDim.x + threadIdx.x;
    if (e < E) {
        atomicAdd(&degin[dst[e]], 1);
        atomicAdd(&degout[src[e]], 1);
    }
}

// exclusive scan of degin[N] -> cursor[N], single block of 1024
__global__ void k_scan(const int* __restrict__ deg, int* __restrict__ cursor, int N) {
    __shared__ int sh[1024];
    const int T = 1024;
    int t = threadIdx.x;
    int chunk = (N + T - 1) / T;
    int base = t * chunk;
    int s = 0;
    for (int i = 0; i < chunk; i++) {
        int idx = base + i;
        if (idx < N) s += deg[idx];
    }
    sh[t] = s;
    __syncthreads();
    for (int off = 1; off < T; off <<= 1) {
        int v = (t >= off) ? sh[t - off] : 0;
        __syncthreads();
        sh[t] += v;
        __syncthreads();
    }
    int ex = (t == 0) ? 0 : sh[t - 1];
    for (int i = 0; i < chunk; i++) {
        int idx = base + i;
        if (idx < N) {
            cursor[idx] = ex;
            ex += deg[idx];
        }
    }
}

__global__ void k_invsqrt2(const int* __restrict__ degin, const int* __restrict__ degout,
                           float* __restrict__ din, float* __restrict__ dout, int N) {
    int i = blockIdx.x * blockDim.x + threadIdx.x;
    if (i < N) {
        int a = degin[i]; if (a < 1) a = 1;
        int b = degout[i]; if (b < 1) b = 1;
        din[i] = rsqrtf((float)a);
        dout[i] = rsqrtf((float)b);
    }
}

// scatter edges into CSR; after this, cursor[v] == row_end(v)
__global__ void k_scatter(const int* __restrict__ src, const int* __restrict__ dst,
                          int* __restrict__ cursor, int* __restrict__ cols, int E) {
    int e = blockIdx.x * blockDim.x + threadIdx.x;
    if (e < E) {
        int p = atomicAdd(&cursor[dst[e]], 1);
        cols[p] = src[e];
    }
}

// ---------------- pull-mode SpMM (D=64), fused epilogues ----------------
// acc[v] = sum_{s in row v} x[s] * (gscale ? gscale[s] : 1)
// if (fsub)          y[v] = fsub[v] - acc * din_row[v]            (Laplacian)
// else: if (rowscale) acc *= rowscale[v]; if (bias) acc += bias; if (relu) max0; y = acc
template <int D>
__launch_bounds__(256)
__global__ void k_spmm_pull(const float* __restrict__ x, const int* __restrict__ cols,
                            const int* __restrict__ cursor, const int* __restrict__ deg,
                            const float* __restrict__ gscale, const float* __restrict__ fsub,
                            const float* __restrict__ rowscale, const float* __restrict__ bias,
                            int relu, float* __restrict__ y, int N) {
    constexpr int TPR = D / 4;              // lanes per row (float4 each)
    constexpr int RPB = 256 / TPR;          // rows per block
    int tid = threadIdx.x;
    int r = tid / TPR, c = tid % TPR;
    int row = blockIdx.x * RPB + r;
    if (row >= N) return;
    int end = cursor[row];
    int start = end - deg[row];
    float4 acc = {0.f, 0.f, 0.f, 0.f};
    const float4* x4 = (const float4*)x;
    int e = start;
    int s_next = (e < end) ? cols[e] : 0;
    for (; e < end; e++) {
        int s = s_next;
        if (e + 1 < end) s_next = cols[e + 1];
        float sc = gscale ? gscale[s] : 1.f;
        float4 v = x4[(size_t)s * TPR + c];
        acc.x += v.x * sc; acc.y += v.y * sc; acc.z += v.z * sc; acc.w += v.w * sc;
    }
    size_t oidx = (size_t)row * TPR + c;
    if (fsub) {
        float d = rowscale[row];
        float4 f = ((const float4*)fsub)[oidx];
        acc.x = f.x - acc.x * d; acc.y = f.y - acc.y * d;
        acc.z = f.z - acc.z * d; acc.w = f.w - acc.w * d;
    } else {
        if (rowscale) {
            float d = rowscale[row];
            acc.x *= d; acc.y *= d; acc.z *= d; acc.w *= d;
        }
        if (bias) {
            const float4 b = ((const float4*)bias)[c];
            acc.x += b.x; acc.y += b.y; acc.z += b.z; acc.w += b.w;
        }
        if (relu) {
            acc.x = fmaxf(acc.x, 0.f); acc.y = fmaxf(acc.y, 0.f);
            acc.z = fmaxf(acc.z, 0.f); acc.w = fmaxf(acc.w, 0.f);
        }
    }
    ((float4*)y)[oidx] = acc;
}

// combine W3 branch blocks into 3 effective [64,64] weights
__global__ void k_wc(const float* __restrict__ W3, float* __restrict__ wc) {
    int i = blockIdx.x * blockDim.x + threadIdx.x;  // 4096
    if (i >= 4096) return;
    int r = i >> 6, c = i & 63;
    float w0 = W3[(0 * 64 + r) * 64 + c];
    float w1 = W3[(1 * 64 + r) * 64 + c];
    float w2 = W3[(2 * 64 + r) * 64 + c];
    float w3 = W3[(3 * 64 + r) * 64 + c];
    float w4 = W3[(4 * 64 + r) * 64 + c];
    wc[i]        = 3.f * w0;                                   // coeff of h
    wc[4096 + i] = -3.f * w0 + 3.f * w1 + w3;                  // coeff of L1 h
    wc[8192 + i] = 0.75f * w0 - 1.5f * w1 + 0.75f * w2 + w4;   // coeff of L2 h
}

// ---------------- generic f32 GEMM: C[N,M] = relu?( A[N,K] @ W[K,M] + bias ) ----------------

struct ASeg { const float* p; int ld; };
struct AArgs { ASeg s[3]; };

template <int M, bool RELU>
__launch_bounds__(256)
__global__ void k_gemm(AArgs A, int K, const float* __restrict__ W,
                       const float* __restrict__ bias, const float* __restrict__ rscale,
                       float* __restrict__ C, int N) {
    constexpr int TX = M / 8;        // threads along cols (8 outputs each)
    constexpr int ROWS = 256 / TX;   // rows per block
    __shared__ float Ws[64 * M];
    __shared__ float As[ROWS * 65];
    int tx = threadIdx.x, ty = threadIdx.y;
    int tid = ty * TX + tx;
    int row0 = blockIdx.x * ROWS;
    float acc[8];
#pragma unroll
    for (int j = 0; j < 8; j++) acc[j] = 0.f;
    int nt = K / 64;
    for (int t = 0; t < nt; t++) {
        const float* Ap = A.s[t].p;
        int ld = A.s[t].ld;
        for (int i = tid; i < ROWS * 64; i += 256) {
            int r = i >> 6, k = i & 63;
            int row = row0 + r;
            float v = 0.f;
            if (row < N) {
                v = Ap[(size_t)row * ld + k];
                if (rscale) v *= rscale[row];
            }
            As[r * 65 + k] = v;
        }
        const float* Wt = W + t * 64 * M;
        for (int i = tid; i < 64 * M; i += 256) Ws[i] = Wt[i];
        __syncthreads();
#pragma unroll 4
        for (int k = 0; k < 64; k++) {
            float av = As[ty * 65 + k];
#pragma unroll
            for (int j = 0; j < 8; j++) acc[j] += av * Ws[k * M + tx * 8 + j];
        }
        __syncthreads();
    }
    int row = row0 + ty;
    if (row < N) {
#pragma unroll
        for (int j = 0; j < 8; j++) {
            float v = acc[j] + (bias ? bias[tx * 8 + j] : 0.f);
            if (RELU) v = fmaxf(v, 0.f);
            C[(size_t)row * M + tx * 8 + j] = v;
        }
    }
}

// out[N,2] = P[N,64] @ W4[64,2] + b4 — 4 lanes per node, shuffle reduce
__global__ void k_out(const float* __restrict__ P, const float* __restrict__ W4,
                      const float* __restrict__ b4, float* __restrict__ out, int N) {
    __shared__ float Ws[128];
    int tid = threadIdx.x;
    if (tid < 128) Ws[tid] = W4[tid];
    __syncthreads();
    int g = blockIdx.x * 64 + (tid >> 2);  // node
    int q = tid & 3;
    float a0 = 0.f, a1 = 0.f;
    if (g < N) {
        const float4* Pr = (const float4*)(P + (size_t)g * 64);
#pragma unroll
        for (int j = 0; j < 4; j++) {
            float4 v = Pr[q * 4 + j];
            int k = q * 16 + j * 4;
            a0 += v.x * Ws[(k + 0) * 2] + v.y * Ws[(k + 1) * 2] +
                  v.z * Ws[(k + 2) * 2] + v.w * Ws[(k + 3) * 2];
            a1 += v.x * Ws[(k + 0) * 2 + 1] + v.y * Ws[(k + 1) * 2 + 1] +
                  v.z * Ws[(k + 2) * 2 + 1] + v.w * Ws[(k + 3) * 2 + 1];
        }
    }
    a0 += __shfl_down(a0, 2); a0 += __shfl_down(a0, 1);
    a1 += __shfl_down(a1, 2); a1 += __shfl_down(a1, 1);
    if (g < N && q == 0) {
        out[(size_t)g * 2 + 0] = a0 + b4[0];
        out[(size_t)g * 2 + 1] = a1 + b4[1];
    }
}

extern "C" void kernel_launch(void* const* d_in, const int* in_sizes, int n_in,
                              void* d_out, int out_size, void* d_ws, size_t ws_size,
                              hipStream_t stream) {
    const int N = NN, E = NE;
    const float* in_feat = (const float*)d_in[0];
    const int* src = (const int*)d_in[1];
    const int* dst = (const int*)d_in[2];
    const float* W1 = (const float*)d_in[3];
    const float* b1 = (const float*)d_in[4];
    const float* W2 = (const float*)d_in[5];
    const float* b2 = (const float*)d_in[6];
    const float* W3 = (const float*)d_in[7];
    const float* b3 = (const float*)d_in[8];
    const float* W4 = (const float*)d_in[9];
    const float* b4 = (const float*)d_in[10];
    const float* Wg1 = (const float*)d_in[11];
    const float* bg1 = (const float*)d_in[12];
    const float* Wg2 = (const float*)d_in[13];
    const float* bg2 = (const float*)d_in[14];

    float* out = (float*)d_out;                 // [N,2]
    float* emb = out + (size_t)N * 2;           // [N,128]

    // workspace layout
    float* fw = (float*)d_ws;
    float* din  = fw;                 // [N]
    float* dout = din + N;            // [N]
    float* bufA = dout + N;           // [N,64]  h1 -> L2 -> Z(gcn)
    float* bufH = bufA + (size_t)64 * N;   // [N,64]  h
    float* bufL1 = bufH + (size_t)64 * N;  // [N,64]  L1 -> g1
    float* S64  = bufL1 + (size_t)64 * N;  // [N,64]  P -> gcn spmm2
    float* wc   = S64 + (size_t)64 * N;    // [3,64,64]
    int* degin  = (int*)(wc + 3 * 4096);   // [N]
    int* degout = degin + N;               // [N]
    int* cursor = degout + N;              // [N]
    int* cols   = cursor + N;              // [E]

    dim3 blk64(8, 32);    // M=64
    dim3 blk128(16, 16);  // M=128
    int gemmBlocks64 = cdiv(N, 32);
    int gemmBlocks128 = cdiv(N, 16);
    int spmmBlocks = cdiv(N, 16);   // 16 rows/block, D=64

    // ---- CSR + degree norms ----
    k_zero_i<<<cdiv(2 * N, 256), 256, 0, stream>>>(degin, 2 * N);
    k_hist<<<cdiv(E, 256), 256, 0, stream>>>(src, dst, degin, degout, E);
    k_scan<<<1, 1024, 0, stream>>>(degin, cursor, N);
    k_invsqrt2<<<cdiv(N, 256), 256, 0, stream>>>(degin, degout, din, dout, N);
    k_scatter<<<cdiv(E, 256), 256, 0, stream>>>(src, dst, cursor, cols, E);

    // ---- h = relu(relu(in_feat@W1+b1)@W2+b2) ----
    AArgs a1; a1.s[0] = {in_feat, 128}; a1.s[1] = {in_feat + 64, 128}; a1.s[2] = {nullptr, 0};
    k_gemm<64, true><<<gemmBlocks64, blk64, 0, stream>>>(a1, 128, W1, b1, nullptr, bufA, N);
    AArgs a2; a2.s[0] = {bufA, 64}; a2.s[1] = {nullptr, 0}; a2.s[2] = {nullptr, 0};
    k_gemm<64, true><<<gemmBlocks64, blk64, 0, stream>>>(a2, 64, W2, b2, nullptr, bufH, N);

    // ---- L1 = lap(h), L2 = lap(L1)  (fused pull spmm) ----
    k_spmm_pull<64><<<spmmBlocks, 256, 0, stream>>>(bufH, cols, cursor, degin,
        din, bufH, din, nullptr, 0, bufL1, N);
    k_spmm_pull<64><<<spmmBlocks, 256, 0, stream>>>(bufL1, cols, cursor, degin,
        din, bufL1, din, nullptr, 0, bufA, N);   // L2 -> bufA

    // ---- P = relu([h|L1|L2]@Wc + b3), out = P@W4+b4 ----
    k_wc<<<16, 256, 0, stream>>>(W3, wc);
    AArgs a3; a3.s[0] = {bufH, 64}; a3.s[1] = {bufL1, 64}; a3.s[2] = {bufA, 64};
    k_gemm<64, true><<<gemmBlocks64, blk64, 0, stream>>>(a3, 192, wc, b3, nullptr, S64, N);
    k_out<<<cdiv(N, 64), 256, 0, stream>>>(S64, W4, b4, out, N);

    // ---- GCN branch (projection commuted before spmm) ----
    // Z = (in_feat * dout) @ Wg1   -> bufA
    AArgs a5; a5.s[0] = {in_feat, 128}; a5.s[1] = {in_feat + 64, 128}; a5.s[2] = {nullptr, 0};
    k_gemm<64, false><<<gemmBlocks64, blk64, 0, stream>>>(a5, 128, Wg1, nullptr, dout, bufA, N);
    // g1 = relu(spmm(Z) * din + bg1) -> bufL1
    k_spmm_pull<64><<<spmmBlocks, 256, 0, stream>>>(bufA, cols, cursor, degin,
        nullptr, nullptr, din, bg1, 1, bufL1, N);
    // S64 = spmm(g1 * dout)
    k_spmm_pull<64><<<spmmBlocks, 256, 0, stream>>>(bufL1, cols, cursor, degin,
        dout, nullptr, nullptr, nullptr, 0, S64, N);
    // emb = (S64 * din) @ Wg2 + bg2
    AArgs a6; a6.s[0] = {S64, 64}; a6.s[1] = {nullptr, 0}; a6.s[2] = {nullptr, 0};
    k_gemm<128, false><<<gemmBlocks128, blk128, 0, stream>>>(a6, 64, Wg2, bg2, din, emb, N);
}

// Round 3
// 452.933 us; speedup vs baseline: 8.0275x; 1.3212x over previous
//
#include <hip/hip_runtime.h>
#include <hip/hip_bf16.h>
#include <math.h>

#define NN 50000
#define NE 800000

static inline int cdiv(int a, int b) { return (a + b - 1) / b; }

// ---------------- CSR build ----------------

__global__ void k_zero_i(int* __restrict__ p, int n) {
    int i = blockIdx.x * blockDim.x + threadIdx.x;
    if (i < n) p[i] = 0;
}

__global__ void k_hist(const int* __restrict__ src, const int* __restrict__ dst,
                       int* __restrict__ degin, int* __restrict__ degout, int E) {
    int e = blockIdx.x * blockDim.x + threadIdx.x;
    if (e < E) {
        atomicAdd(&degin[dst[e]], 1);
        atomicAdd(&degout[src[e]], 1);
    }
}

// ---- parallel exclusive scan: A) per-block scan + block sums, B) scan sums, C) add offsets ----

__global__ void k_scanA(const int* __restrict__ deg, int* __restrict__ cursor,
                        int* __restrict__ bsum, int N) {
    __shared__ int sh[256];
    int t = threadIdx.x;
    int i = blockIdx.x * 256 + t;
    int v = (i < N) ? deg[i] : 0;
    sh[t] = v;
    __syncthreads();
    for (int off = 1; off < 256; off <<= 1) {
        int y = (t >= off) ? sh[t - off] : 0;
        __syncthreads();
        sh[t] += y;
        __syncthreads();
    }
    if (i < N) cursor[i] = sh[t] - v;   // local exclusive
    if (t == 255) bsum[blockIdx.x] = sh[255];
}

__global__ void k_scanB(int* __restrict__ bsum, int* __restrict__ boff, int nb) {
    __shared__ int sh[256];
    int t = threadIdx.x;
    int v = (t < nb) ? bsum[t] : 0;
    sh[t] = v;
    __syncthreads();
    for (int off = 1; off < 256; off <<= 1) {
        int y = (t >= off) ? sh[t - off] : 0;
        __syncthreads();
        sh[t] += y;
        __syncthreads();
    }
    if (t < nb) boff[t] = sh[t] - v;
}

__global__ void k_scanC(int* __restrict__ cursor, const int* __restrict__ boff, int N) {
    int i = blockIdx.x * blockDim.x + threadIdx.x;
    if (i < N) cursor[i] += boff[blockIdx.x];
}

__global__ void k_invsqrt2(const int* __restrict__ degin, const int* __restrict__ degout,
                           float* __restrict__ din, float* __restrict__ dout, int N) {
    int i = blockIdx.x * blockDim.x + threadIdx.x;
    if (i < N) {
        int a = degin[i]; if (a < 1) a = 1;
        int b = degout[i]; if (b < 1) b = 1;
        din[i] = rsqrtf((float)a);
        dout[i] = rsqrtf((float)b);
    }
}

// scatter edges into CSR; after this, cursor[v] == row_end(v)
__global__ void k_scatter(const int* __restrict__ src, const int* __restrict__ dst,
                          int* __restrict__ cursor, int* __restrict__ cols, int E) {
    int e = blockIdx.x * blockDim.x + threadIdx.x;
    if (e < E) {
        int p = atomicAdd(&cursor[dst[e]], 1);
        cols[p] = src[e];
    }
}

// ---------------- pull-mode SpMM (D=64), fused epilogues ----------------
template <int D>
__launch_bounds__(256)
__global__ void k_spmm_pull(const float* __restrict__ x, const int* __restrict__ cols,
                            const int* __restrict__ cursor, const int* __restrict__ deg,
                            const float* __restrict__ gscale, const float* __restrict__ fsub,
                            const float* __restrict__ rowscale, const float* __restrict__ bias,
                            int relu, float* __restrict__ y, int N) {
    constexpr int TPR = D / 4;              // lanes per row (float4 each)
    constexpr int RPB = 256 / TPR;          // rows per block
    int tid = threadIdx.x;
    int r = tid / TPR, c = tid % TPR;
    int row = blockIdx.x * RPB + r;
    if (row >= N) return;
    int end = cursor[row];
    int start = end - deg[row];
    float4 acc = {0.f, 0.f, 0.f, 0.f};
    const float4* x4 = (const float4*)x;
    int e = start;
    int s_next = (e < end) ? cols[e] : 0;
    for (; e < end; e++) {
        int s = s_next;
        if (e + 1 < end) s_next = cols[e + 1];
        float sc = gscale ? gscale[s] : 1.f;
        float4 v = x4[(size_t)s * TPR + c];
        acc.x += v.x * sc; acc.y += v.y * sc; acc.z += v.z * sc; acc.w += v.w * sc;
    }
    size_t oidx = (size_t)row * TPR + c;
    if (fsub) {
        float d = rowscale[row];
        float4 f = ((const float4*)fsub)[oidx];
        acc.x = f.x - acc.x * d; acc.y = f.y - acc.y * d;
        acc.z = f.z - acc.z * d; acc.w = f.w - acc.w * d;
    } else {
        if (rowscale) {
            float d = rowscale[row];
            acc.x *= d; acc.y *= d; acc.z *= d; acc.w *= d;
        }
        if (bias) {
            const float4 b = ((const float4*)bias)[c];
            acc.x += b.x; acc.y += b.y; acc.z += b.z; acc.w += b.w;
        }
        if (relu) {
            acc.x = fmaxf(acc.x, 0.f); acc.y = fmaxf(acc.y, 0.f);
            acc.z = fmaxf(acc.z, 0.f); acc.w = fmaxf(acc.w, 0.f);
        }
    }
    ((float4*)y)[oidx] = acc;
}

// combine W3 branch blocks into 3 effective [64,64] weights
__global__ void k_wc(const float* __restrict__ W3, float* __restrict__ wc) {
    int i = blockIdx.x * blockDim.x + threadIdx.x;  // 4096
    if (i >= 4096) return;
    int r = i >> 6, c = i & 63;
    float w0 = W3[(0 * 64 + r) * 64 + c];
    float w1 = W3[(1 * 64 + r) * 64 + c];
    float w2 = W3[(2 * 64 + r) * 64 + c];
    float w3 = W3[(3 * 64 + r) * 64 + c];
    float w4 = W3[(4 * 64 + r) * 64 + c];
    wc[i]        = 3.f * w0;
    wc[4096 + i] = -3.f * w0 + 3.f * w1 + w3;
    wc[8192 + i] = 0.75f * w0 - 1.5f * w1 + 0.75f * w2 + w4;
}

// ---------------- register-tiled f32 GEMM: C[N,M] = relu?( A[N,K] @ W[K,M] + bias ) ----------------
// 4x4 micro-tile per thread; A staged transposed (k-major) so both operands are ds_read_b128.

struct ASeg { const float* p; int ld; };
struct AArgs { ASeg s[3]; };

template <int M, bool RELU>
__launch_bounds__(256)
__global__ void k_gemm_rt(AArgs A, int K, const float* __restrict__ W,
                          const float* __restrict__ bias, const float* __restrict__ rscale,
                          float* __restrict__ C, int N) {
    constexpr int TX = M / 4;          // threads along cols: 16 (M=64) / 32 (M=128)
    constexpr int TYN = 256 / TX;      // 16 / 8
    constexpr int BM = TYN * 4;        // rows per block: 64 / 32
    constexpr int AP = BM + 4;         // padded transposed-A leading dim (16B-aligned rows)
    __shared__ float At[64 * AP];
    __shared__ float Ws[64 * M];
    int tid = threadIdx.x;
    int tx = tid % TX, ty = tid / TX;
    int row0 = blockIdx.x * BM;
    float acc[4][4] = {{0.f}};
    int nt = K / 64;
    for (int t = 0; t < nt; t++) {
        const float* Ap = A.s[t].p;
        int ld = A.s[t].ld;
        // stage A transposed: thread reads float4 along k, scatters to k-major LDS
        {
            int kk = (tid % 16) * 4;
            for (int r = tid / 16; r < BM; r += 16) {
                int row = row0 + r;
                float4 v = {0.f, 0.f, 0.f, 0.f};
                if (row < N) {
                    v = *(const float4*)(Ap + (size_t)row * ld + kk);
                    if (rscale) { float s = rscale[row]; v.x *= s; v.y *= s; v.z *= s; v.w *= s; }
                }
                At[(kk + 0) * AP + r] = v.x;
                At[(kk + 1) * AP + r] = v.y;
                At[(kk + 2) * AP + r] = v.z;
                At[(kk + 3) * AP + r] = v.w;
            }
        }
        // stage W tile (row-major, direct copy)
        {
            const float* Wt = W + t * 64 * M;
            for (int i = tid * 4; i < 64 * M; i += 1024)
                *(float4*)(Ws + i) = *(const float4*)(Wt + i);
        }
        __syncthreads();
#pragma unroll 16
        for (int k = 0; k < 64; k++) {
            float4 a = *(const float4*)(At + k * AP + ty * 4);
            float4 w = *(const float4*)(Ws + k * M + tx * 4);
            acc[0][0] += a.x * w.x; acc[0][1] += a.x * w.y; acc[0][2] += a.x * w.z; acc[0][3] += a.x * w.w;
            acc[1][0] += a.y * w.x; acc[1][1] += a.y * w.y; acc[1][2] += a.y * w.z; acc[1][3] += a.y * w.w;
            acc[2][0] += a.z * w.x; acc[2][1] += a.z * w.y; acc[2][2] += a.z * w.z; acc[2][3] += a.z * w.w;
            acc[3][0] += a.w * w.x; acc[3][1] += a.w * w.y; acc[3][2] += a.w * w.z; acc[3][3] += a.w * w.w;
        }
        __syncthreads();
    }
    float4 b = {0.f, 0.f, 0.f, 0.f};
    if (bias) b = *(const float4*)(bias + tx * 4);
#pragma unroll
    for (int i = 0; i < 4; i++) {
        int row = row0 + ty * 4 + i;
        if (row < N) {
            float4 o;
            o.x = acc[i][0] + b.x; o.y = acc[i][1] + b.y;
            o.z = acc[i][2] + b.z; o.w = acc[i][3] + b.w;
            if (RELU) {
                o.x = fmaxf(o.x, 0.f); o.y = fmaxf(o.y, 0.f);
                o.z = fmaxf(o.z, 0.f); o.w = fmaxf(o.w, 0.f);
            }
            *(float4*)(C + (size_t)row * M + tx * 4) = o;
        }
    }
}

// out[N,2] = P[N,64] @ W4[64,2] + b4
__global__ void k_out(const float* __restrict__ P, const float* __restrict__ W4,
                      const float* __restrict__ b4, float* __restrict__ out, int N) {
    __shared__ float Ws[128];
    int tid = threadIdx.x;
    if (tid < 128) Ws[tid] = W4[tid];
    __syncthreads();
    int g = blockIdx.x * 64 + (tid >> 2);
    int q = tid & 3;
    float a0 = 0.f, a1 = 0.f;
    if (g < N) {
        const float4* Pr = (const float4*)(P + (size_t)g * 64);
#pragma unroll
        for (int j = 0; j < 4; j++) {
            float4 v = Pr[q * 4 + j];
            int k = q * 16 + j * 4;
            a0 += v.x * Ws[(k + 0) * 2] + v.y * Ws[(k + 1) * 2] +
                  v.z * Ws[(k + 2) * 2] + v.w * Ws[(k + 3) * 2];
            a1 += v.x * Ws[(k + 0) * 2 + 1] + v.y * Ws[(k + 1) * 2 + 1] +
                  v.z * Ws[(k + 2) * 2 + 1] + v.w * Ws[(k + 3) * 2 + 1];
        }
    }
    a0 += __shfl_down(a0, 2); a0 += __shfl_down(a0, 1);
    a1 += __shfl_down(a1, 2); a1 += __shfl_down(a1, 1);
    if (g < N && q == 0) {
        out[(size_t)g * 2 + 0] = a0 + b4[0];
        out[(size_t)g * 2 + 1] = a1 + b4[1];
    }
}

extern "C" void kernel_launch(void* const* d_in, const int* in_sizes, int n_in,
                              void* d_out, int out_size, void* d_ws, size_t ws_size,
                              hipStream_t stream) {
    const int N = NN, E = NE;
    const float* in_feat = (const float*)d_in[0];
    const int* src = (const int*)d_in[1];
    const int* dst = (const int*)d_in[2];
    const float* W1 = (const float*)d_in[3];
    const float* b1 = (const float*)d_in[4];
    const float* W2 = (const float*)d_in[5];
    const float* b2 = (const float*)d_in[6];
    const float* W3 = (const float*)d_in[7];
    const float* b3 = (const float*)d_in[8];
    const float* W4 = (const float*)d_in[9];
    const float* b4 = (const float*)d_in[10];
    const float* Wg1 = (const float*)d_in[11];
    const float* bg1 = (const float*)d_in[12];
    const float* Wg2 = (const float*)d_in[13];
    const float* bg2 = (const float*)d_in[14];

    float* out = (float*)d_out;                 // [N,2]
    float* emb = out + (size_t)N * 2;           // [N,128]

    // workspace layout
    float* fw = (float*)d_ws;
    float* din  = fw;                 // [N]
    float* dout = din + N;            // [N]
    float* bufA = dout + N;           // [N,64]
    float* bufH = bufA + (size_t)64 * N;   // [N,64]
    float* bufL1 = bufH + (size_t)64 * N;  // [N,64]
    float* S64  = bufL1 + (size_t)64 * N;  // [N,64]
    float* wc   = S64 + (size_t)64 * N;    // [3,64,64]
    int* degin  = (int*)(wc + 3 * 4096);   // [N]
    int* degout = degin + N;               // [N]
    int* cursor = degout + N;              // [N]
    int* cols   = cursor + N;              // [E]
    int* bsum   = cols + E;                // [nb]
    int* boff   = bsum + 256;              // [nb]

    int gemmBlocks64 = cdiv(N, 64);
    int gemmBlocks128 = cdiv(N, 32);
    int spmmBlocks = cdiv(N, 16);   // 16 rows/block, D=64
    int nb = cdiv(N, 256);

    // ---- CSR + degree norms ----
    k_zero_i<<<cdiv(2 * N, 256), 256, 0, stream>>>(degin, 2 * N);
    k_hist<<<cdiv(E, 256), 256, 0, stream>>>(src, dst, degin, degout, E);
    k_scanA<<<nb, 256, 0, stream>>>(degin, cursor, bsum, N);
    k_scanB<<<1, 256, 0, stream>>>(bsum, boff, nb);
    k_scanC<<<nb, 256, 0, stream>>>(cursor, boff, N);
    k_invsqrt2<<<cdiv(N, 256), 256, 0, stream>>>(degin, degout, din, dout, N);
    k_scatter<<<cdiv(E, 256), 256, 0, stream>>>(src, dst, cursor, cols, E);

    // ---- h = relu(relu(in_feat@W1+b1)@W2+b2) ----
    AArgs a1; a1.s[0] = {in_feat, 128}; a1.s[1] = {in_feat + 64, 128}; a1.s[2] = {nullptr, 0};
    k_gemm_rt<64, true><<<gemmBlocks64, 256, 0, stream>>>(a1, 128, W1, b1, nullptr, bufA, N);
    AArgs a2; a2.s[0] = {bufA, 64}; a2.s[1] = {nullptr, 0}; a2.s[2] = {nullptr, 0};
    k_gemm_rt<64, true><<<gemmBlocks64, 256, 0, stream>>>(a2, 64, W2, b2, nullptr, bufH, N);

    // ---- L1 = lap(h), L2 = lap(L1) ----
    k_spmm_pull<64><<<spmmBlocks, 256, 0, stream>>>(bufH, cols, cursor, degin,
        din, bufH, din, nullptr, 0, bufL1, N);
    k_spmm_pull<64><<<spmmBlocks, 256, 0, stream>>>(bufL1, cols, cursor, degin,
        din, bufL1, din, nullptr, 0, bufA, N);   // L2 -> bufA

    // ---- P = relu([h|L1|L2]@Wc + b3), out = P@W4+b4 ----
    k_wc<<<16, 256, 0, stream>>>(W3, wc);
    AArgs a3; a3.s[0] = {bufH, 64}; a3.s[1] = {bufL1, 64}; a3.s[2] = {bufA, 64};
    k_gemm_rt<64, true><<<gemmBlocks64, 256, 0, stream>>>(a3, 192, wc, b3, nullptr, S64, N);
    k_out<<<cdiv(N, 64), 256, 0, stream>>>(S64, W4, b4, out, N);

    // ---- GCN branch (projection commuted before spmm) ----
    AArgs a5; a5.s[0] = {in_feat, 128}; a5.s[1] = {in_feat + 64, 128}; a5.s[2] = {nullptr, 0};
    k_gemm_rt<64, false><<<gemmBlocks64, 256, 0, stream>>>(a5, 128, Wg1, nullptr, dout, bufA, N);
    k_spmm_pull<64><<<spmmBlocks, 256, 0, stream>>>(bufA, cols, cursor, degin,
        nullptr, nullptr, din, bg1, 1, bufL1, N);
    k_spmm_pull<64><<<spmmBlocks, 256, 0, stream>>>(bufL1, cols, cursor, degin,
        dout, nullptr, nullptr, nullptr, 0, S64, N);
    AArgs a6; a6.s[0] = {S64, 64}; a6.s[1] = {nullptr, 0}; a6.s[2] = {nullptr, 0};
    k_gemm_rt<128, false><<<gemmBlocks128, 256, 0, stream>>>(a6, 64, Wg2, bg2, din, emb, N);
}

// Round 4
// 426.533 us; speedup vs baseline: 8.5244x; 1.0619x over previous
//
#include <hip/hip_runtime.h>
#include <hip/hip_bf16.h>
#include <math.h>

#define NN 50000
#define NE 800000

typedef _Float16 half4v __attribute__((ext_vector_type(4)));

static inline int cdiv(int a, int b) { return (a + b - 1) / b; }

// ---------------- CSR build ----------------

__global__ void k_zero_i(int* __restrict__ p, int n) {
    int i = blockIdx.x * blockDim.x + threadIdx.x;
    if (i < n) p[i] = 0;
}

__global__ void k_hist(const int* __restrict__ src, const int* __restrict__ dst,
                       int* __restrict__ degin, int* __restrict__ degout, int E) {
    int idx = blockIdx.x * blockDim.x + threadIdx.x;
    int nthr = gridDim.x * blockDim.x;
#pragma unroll
    for (int j = 0; j < 4; j++) {
        int e = idx + j * nthr;
        if (e < E) {
            atomicAdd(&degin[dst[e]], 1);
            atomicAdd(&degout[src[e]], 1);
        }
    }
}

// ---- parallel exclusive scan ----

__global__ void k_scanA(const int* __restrict__ deg, int* __restrict__ cursor,
                        int* __restrict__ bsum, int N) {
    __shared__ int sh[256];
    int t = threadIdx.x;
    int i = blockIdx.x * 256 + t;
    int v = (i < N) ? deg[i] : 0;
    sh[t] = v;
    __syncthreads();
    for (int off = 1; off < 256; off <<= 1) {
        int y = (t >= off) ? sh[t - off] : 0;
        __syncthreads();
        sh[t] += y;
        __syncthreads();
    }
    if (i < N) cursor[i] = sh[t] - v;
    if (t == 255) bsum[blockIdx.x] = sh[255];
}

__global__ void k_scanB(int* __restrict__ bsum, int* __restrict__ boff, int nb) {
    __shared__ int sh[256];
    int t = threadIdx.x;
    int v = (t < nb) ? bsum[t] : 0;
    sh[t] = v;
    __syncthreads();
    for (int off = 1; off < 256; off <<= 1) {
        int y = (t >= off) ? sh[t - off] : 0;
        __syncthreads();
        sh[t] += y;
        __syncthreads();
    }
    if (t < nb) boff[t] = sh[t] - v;
}

// fused: add block offsets + compute din/dout
__global__ void k_scanC_inv(int* __restrict__ cursor, const int* __restrict__ boff,
                            const int* __restrict__ degin, const int* __restrict__ degout,
                            float* __restrict__ din, float* __restrict__ dout, int N) {
    int i = blockIdx.x * blockDim.x + threadIdx.x;
    if (i < N) {
        cursor[i] += boff[blockIdx.x];
        int a = degin[i]; if (a < 1) a = 1;
        int b = degout[i]; if (b < 1) b = 1;
        din[i] = rsqrtf((float)a);
        dout[i] = rsqrtf((float)b);
    }
}

__global__ void k_scatter(const int* __restrict__ src, const int* __restrict__ dst,
                          int* __restrict__ cursor, int* __restrict__ cols, int E) {
    int e = blockIdx.x * blockDim.x + threadIdx.x;
    if (e < E) {
        int p = atomicAdd(&cursor[dst[e]], 1);
        cols[p] = src[e];
    }
}

// ---------------- pull-mode SpMM, fp16 gather table, f32 accumulate ----------------
// acc[v] = sum_{s in row v} xh[s]          (xh is pre-scaled by producer)
// if (fsub)  yv = fsub[v] - acc * rowscale[v]        (Laplacian)
// else       yv = acc; if(rowscale) *=; if(bias) +=; if(relu) max0
// if (y)  write f32 yv;  if (yh) write half(yv * mscale[v])  (mscale nullable -> 1)
__launch_bounds__(256)
__global__ void k_spmm_pull_h(const half4v* __restrict__ xh, const int* __restrict__ cols,
                              const int* __restrict__ cursor, const int* __restrict__ deg,
                              const float* __restrict__ fsub, const float* __restrict__ rowscale,
                              const float* __restrict__ bias, int relu,
                              float* __restrict__ y, half4v* __restrict__ yh,
                              const float* __restrict__ mscale, int N) {
    constexpr int TPR = 16;             // lanes per row, half4 (8B) each
    constexpr int RPB = 256 / TPR;      // 16 rows per block
    int tid = threadIdx.x;
    int r = tid / TPR, c = tid % TPR;
    int row = blockIdx.x * RPB + r;
    if (row >= N) return;
    int end = cursor[row];
    int start = end - deg[row];
    float4 acc = {0.f, 0.f, 0.f, 0.f};
    int e = start;
    int s_next = (e < end) ? cols[e] : 0;
    for (; e < end; e++) {
        int s = s_next;
        if (e + 1 < end) s_next = cols[e + 1];
        half4v v = xh[(size_t)s * TPR + c];
        acc.x += (float)v.x; acc.y += (float)v.y;
        acc.z += (float)v.z; acc.w += (float)v.w;
    }
    size_t oidx = (size_t)row * TPR + c;
    if (fsub) {
        float d = rowscale[row];
        float4 f = ((const float4*)fsub)[oidx];
        acc.x = f.x - acc.x * d; acc.y = f.y - acc.y * d;
        acc.z = f.z - acc.z * d; acc.w = f.w - acc.w * d;
    } else {
        if (rowscale) {
            float d = rowscale[row];
            acc.x *= d; acc.y *= d; acc.z *= d; acc.w *= d;
        }
        if (bias) {
            const float4 b = ((const float4*)bias)[c];
            acc.x += b.x; acc.y += b.y; acc.z += b.z; acc.w += b.w;
        }
        if (relu) {
            acc.x = fmaxf(acc.x, 0.f); acc.y = fmaxf(acc.y, 0.f);
            acc.z = fmaxf(acc.z, 0.f); acc.w = fmaxf(acc.w, 0.f);
        }
    }
    if (y) ((float4*)y)[oidx] = acc;
    if (yh) {
        float m = mscale ? mscale[row] : 1.f;
        half4v hv;
        hv.x = (_Float16)(acc.x * m); hv.y = (_Float16)(acc.y * m);
        hv.z = (_Float16)(acc.z * m); hv.w = (_Float16)(acc.w * m);
        yh[oidx] = hv;
    }
}

// combine W3 branch blocks into 3 effective [64,64] weights
__global__ void k_wc(const float* __restrict__ W3, float* __restrict__ wc) {
    int i = blockIdx.x * blockDim.x + threadIdx.x;  // 4096
    if (i >= 4096) return;
    int r = i >> 6, c = i & 63;
    float w0 = W3[(0 * 64 + r) * 64 + c];
    float w1 = W3[(1 * 64 + r) * 64 + c];
    float w2 = W3[(2 * 64 + r) * 64 + c];
    float w3 = W3[(3 * 64 + r) * 64 + c];
    float w4 = W3[(4 * 64 + r) * 64 + c];
    wc[i]        = 3.f * w0;
    wc[4096 + i] = -3.f * w0 + 3.f * w1 + w3;
    wc[8192 + i] = 0.75f * w0 - 1.5f * w1 + 0.75f * w2 + w4;
}

// ---------------- register-tiled f32 GEMM ----------------
// C[N,M] = relu?( A[N,K] @ W[K,M] + bias );  optional fp16 mirror Ch = half(C * mscale)

struct ASeg { const float* p; int ld; };
struct AArgs { ASeg s[3]; };

template <int M, bool RELU>
__launch_bounds__(256)
__global__ void k_gemm_rt(AArgs A, int K, const float* __restrict__ W,
                          const float* __restrict__ bias, const float* __restrict__ rscale,
                          float* __restrict__ C, half4v* __restrict__ Ch,
                          const float* __restrict__ mscale, int N) {
    constexpr int TX = M / 4;
    constexpr int TYN = 256 / TX;
    constexpr int BM = TYN * 4;
    constexpr int AP = BM + 4;
    __shared__ float At[64 * AP];
    __shared__ float Ws[64 * M];
    int tid = threadIdx.x;
    int tx = tid % TX, ty = tid / TX;
    int row0 = blockIdx.x * BM;
    float acc[4][4] = {{0.f}};
    int nt = K / 64;
    for (int t = 0; t < nt; t++) {
        const float* Ap = A.s[t].p;
        int ld = A.s[t].ld;
        {
            int kk = (tid % 16) * 4;
            for (int r = tid / 16; r < BM; r += 16) {
                int row = row0 + r;
                float4 v = {0.f, 0.f, 0.f, 0.f};
                if (row < N) {
                    v = *(const float4*)(Ap + (size_t)row * ld + kk);
                    if (rscale) { float s = rscale[row]; v.x *= s; v.y *= s; v.z *= s; v.w *= s; }
                }
                At[(kk + 0) * AP + r] = v.x;
                At[(kk + 1) * AP + r] = v.y;
                At[(kk + 2) * AP + r] = v.z;
                At[(kk + 3) * AP + r] = v.w;
            }
        }
        {
            const float* Wt = W + t * 64 * M;
            for (int i = tid * 4; i < 64 * M; i += 1024)
                *(float4*)(Ws + i) = *(const float4*)(Wt + i);
        }
        __syncthreads();
#pragma unroll 16
        for (int k = 0; k < 64; k++) {
            float4 a = *(const float4*)(At + k * AP + ty * 4);
            float4 w = *(const float4*)(Ws + k * M + tx * 4);
            acc[0][0] += a.x * w.x; acc[0][1] += a.x * w.y; acc[0][2] += a.x * w.z; acc[0][3] += a.x * w.w;
            acc[1][0] += a.y * w.x; acc[1][1] += a.y * w.y; acc[1][2] += a.y * w.z; acc[1][3] += a.y * w.w;
            acc[2][0] += a.z * w.x; acc[2][1] += a.z * w.y; acc[2][2] += a.z * w.z; acc[2][3] += a.z * w.w;
            acc[3][0] += a.w * w.x; acc[3][1] += a.w * w.y; acc[3][2] += a.w * w.z; acc[3][3] += a.w * w.w;
        }
        __syncthreads();
    }
    float4 b = {0.f, 0.f, 0.f, 0.f};
    if (bias) b = *(const float4*)(bias + tx * 4);
#pragma unroll
    for (int i = 0; i < 4; i++) {
        int row = row0 + ty * 4 + i;
        if (row < N) {
            float4 o;
            o.x = acc[i][0] + b.x; o.y = acc[i][1] + b.y;
            o.z = acc[i][2] + b.z; o.w = acc[i][3] + b.w;
            if (RELU) {
                o.x = fmaxf(o.x, 0.f); o.y = fmaxf(o.y, 0.f);
                o.z = fmaxf(o.z, 0.f); o.w = fmaxf(o.w, 0.f);
            }
            if (C) *(float4*)(C + (size_t)row * M + tx * 4) = o;
            if (Ch) {
                float m = mscale ? mscale[row] : 1.f;
                half4v hv;
                hv.x = (_Float16)(o.x * m); hv.y = (_Float16)(o.y * m);
                hv.z = (_Float16)(o.z * m); hv.w = (_Float16)(o.w * m);
                Ch[((size_t)row * M + tx * 4) / 4] = hv;
            }
        }
    }
}

// out[N,2] = P[N,64] @ W4[64,2] + b4
__global__ void k_out(const float* __restrict__ P, const float* __restrict__ W4,
                      const float* __restrict__ b4, float* __restrict__ out, int N) {
    __shared__ float Ws[128];
    int tid = threadIdx.x;
    if (tid < 128) Ws[tid] = W4[tid];
    __syncthreads();
    int g = blockIdx.x * 64 + (tid >> 2);
    int q = tid & 3;
    float a0 = 0.f, a1 = 0.f;
    if (g < N) {
        const float4* Pr = (const float4*)(P + (size_t)g * 64);
#pragma unroll
        for (int j = 0; j < 4; j++) {
            float4 v = Pr[q * 4 + j];
            int k = q * 16 + j * 4;
            a0 += v.x * Ws[(k + 0) * 2] + v.y * Ws[(k + 1) * 2] +
                  v.z * Ws[(k + 2) * 2] + v.w * Ws[(k + 3) * 2];
            a1 += v.x * Ws[(k + 0) * 2 + 1] + v.y * Ws[(k + 1) * 2 + 1] +
                  v.z * Ws[(k + 2) * 2 + 1] + v.w * Ws[(k + 3) * 2 + 1];
        }
    }
    a0 += __shfl_down(a0, 2); a0 += __shfl_down(a0, 1);
    a1 += __shfl_down(a1, 2); a1 += __shfl_down(a1, 1);
    if (g < N && q == 0) {
        out[(size_t)g * 2 + 0] = a0 + b4[0];
        out[(size_t)g * 2 + 1] = a1 + b4[1];
    }
}

extern "C" void kernel_launch(void* const* d_in, const int* in_sizes, int n_in,
                              void* d_out, int out_size, void* d_ws, size_t ws_size,
                              hipStream_t stream) {
    const int N = NN, E = NE;
    const float* in_feat = (const float*)d_in[0];
    const int* src = (const int*)d_in[1];
    const int* dst = (const int*)d_in[2];
    const float* W1 = (const float*)d_in[3];
    const float* b1 = (const float*)d_in[4];
    const float* W2 = (const float*)d_in[5];
    const float* b2 = (const float*)d_in[6];
    const float* W3 = (const float*)d_in[7];
    const float* b3 = (const float*)d_in[8];
    const float* W4 = (const float*)d_in[9];
    const float* b4 = (const float*)d_in[10];
    const float* Wg1 = (const float*)d_in[11];
    const float* bg1 = (const float*)d_in[12];
    const float* Wg2 = (const float*)d_in[13];
    const float* bg2 = (const float*)d_in[14];

    float* out = (float*)d_out;                 // [N,2]
    float* emb = out + (size_t)N * 2;           // [N,128]

    // workspace layout
    float* fw = (float*)d_ws;
    float* din  = fw;                      // [N]
    float* dout = din + N;                 // [N]
    float* bufA = dout + N;                // [N,64]  h1 -> L2
    float* bufH = bufA + (size_t)64 * N;   // [N,64]  h
    float* bufL1 = bufH + (size_t)64 * N;  // [N,64]  L1
    float* S64  = bufL1 + (size_t)64 * N;  // [N,64]  P -> gcn spmm2 out
    float* wc   = S64 + (size_t)64 * N;    // [3,64,64]
    half4v* hbuf0 = (half4v*)(wc + 3 * 4096);                    // [N,64] fp16: h*din -> Z
    half4v* hbuf1 = (half4v*)((_Float16*)hbuf0 + (size_t)64 * N); // [N,64] fp16: L1*din -> g1*dout
    int* degin  = (int*)((_Float16*)hbuf1 + (size_t)64 * N);     // [N]
    int* degout = degin + N;               // [N]
    int* cursor = degout + N;              // [N]
    int* cols   = cursor + N;              // [E]
    int* bsum   = cols + E;                // [nb]
    int* boff   = bsum + 256;              // [nb]

    int gemmBlocks64 = cdiv(N, 64);
    int gemmBlocks128 = cdiv(N, 32);
    int spmmBlocks = cdiv(N, 16);
    int nb = cdiv(N, 256);

    // ---- CSR + degree norms ----
    k_zero_i<<<cdiv(2 * N, 256), 256, 0, stream>>>(degin, 2 * N);
    k_hist<<<cdiv(E, 1024), 256, 0, stream>>>(src, dst, degin, degout, E);
    k_scanA<<<nb, 256, 0, stream>>>(degin, cursor, bsum, N);
    k_scanB<<<1, 256, 0, stream>>>(bsum, boff, nb);
    k_scanC_inv<<<nb, 256, 0, stream>>>(cursor, boff, degin, degout, din, dout, N);
    k_scatter<<<cdiv(E, 256), 256, 0, stream>>>(src, dst, cursor, cols, E);

    // ---- h = relu(relu(in_feat@W1+b1)@W2+b2); mirror hbuf0 = half(h*din) ----
    AArgs a1; a1.s[0] = {in_feat, 128}; a1.s[1] = {in_feat + 64, 128}; a1.s[2] = {nullptr, 0};
    k_gemm_rt<64, true><<<gemmBlocks64, 256, 0, stream>>>(a1, 128, W1, b1, nullptr,
        bufA, nullptr, nullptr, N);
    AArgs a2; a2.s[0] = {bufA, 64}; a2.s[1] = {nullptr, 0}; a2.s[2] = {nullptr, 0};
    k_gemm_rt<64, true><<<gemmBlocks64, 256, 0, stream>>>(a2, 64, W2, b2, nullptr,
        bufH, hbuf0, din, N);

    // ---- L1 = lap(h) [mirror hbuf1 = half(L1*din)], L2 = lap(L1) -> bufA ----
    k_spmm_pull_h<<<spmmBlocks, 256, 0, stream>>>(hbuf0, cols, cursor, degin,
        bufH, din, nullptr, 0, bufL1, hbuf1, din, N);
    k_spmm_pull_h<<<spmmBlocks, 256, 0, stream>>>(hbuf1, cols, cursor, degin,
        bufL1, din, nullptr, 0, bufA, nullptr, nullptr, N);

    // ---- P = relu([h|L1|L2]@Wc + b3) -> S64, out = P@W4+b4 ----
    k_wc<<<16, 256, 0, stream>>>(W3, wc);
    AArgs a3; a3.s[0] = {bufH, 64}; a3.s[1] = {bufL1, 64}; a3.s[2] = {bufA, 64};
    k_gemm_rt<64, true><<<gemmBlocks64, 256, 0, stream>>>(a3, 192, wc, b3, nullptr,
        S64, nullptr, nullptr, N);
    k_out<<<cdiv(N, 64), 256, 0, stream>>>(S64, W4, b4, out, N);

    // ---- GCN branch ----
    // Zh = half((in_feat*dout) @ Wg1)   (fp16 only)
    AArgs a5; a5.s[0] = {in_feat, 128}; a5.s[1] = {in_feat + 64, 128}; a5.s[2] = {nullptr, 0};
    k_gemm_rt<64, false><<<gemmBlocks64, 256, 0, stream>>>(a5, 128, Wg1, nullptr, dout,
        nullptr, hbuf0, nullptr, N);
    // g1h = half( relu(spmm(Zh)*din + bg1) * dout )   (fp16 only)
    k_spmm_pull_h<<<spmmBlocks, 256, 0, stream>>>(hbuf0, cols, cursor, degin,
        nullptr, din, bg1, 1, nullptr, hbuf1, dout, N);
    // S64 = spmm(g1h)
    k_spmm_pull_h<<<spmmBlocks, 256, 0, stream>>>(hbuf1, cols, cursor, degin,
        nullptr, nullptr, nullptr, 0, S64, nullptr, nullptr, N);
    // emb = (S64*din) @ Wg2 + bg2
    AArgs a6; a6.s[0] = {S64, 64}; a6.s[1] = {nullptr, 0}; a6.s[2] = {nullptr, 0};
    k_gemm_rt<128, false><<<gemmBlocks128, 256, 0, stream>>>(a6, 64, Wg2, bg2, din,
        emb, nullptr, nullptr, N);
}